// Round 2
// baseline (224.240 us; speedup 1.0000x reference)
//
#include <hip/hip_runtime.h>
#include <hip/hip_bf16.h>
#include <hip/hip_fp16.h>

// MHAHead B=8,S=2048,E=512. R7: fp16 pipeline, structurally safe launcher.
//   - No writes to input buffers (x/mask/weights read-only; replay-idempotent).
//   - d_out written only by gemmO epilogue (no Q/K/S aliasing into d_out or x).
//   - proj converts x fp32/bf16 -> f16 on the fly (reg-staged LDS writes, same
//     XOR-swizzled granule layout as the gld16 path).
//   - S scratch in ws, phased: P batches/phase chosen from ws_size (8/4/2/1).
//     Worst-case ws need = 52.4MB (wb+Q+K+Vt) + 8.4MB (1-batch S) = 60.8MB.
//   conv_w: weights/biases -> f16 in ws
//   proj  : uni GEMM 128x128xBK32; z=2 computes Vt directly
//   gemmS : S = exp(mask? -inf : Q.K^T * scale) f16, phased batches
//   gemmO : out = (S @ Vt) / rowsum(S), rowsum via all-ones-B MFMA column

typedef unsigned short u16;
typedef __attribute__((ext_vector_type(8))) short short8;
typedef __attribute__((ext_vector_type(8))) _Float16 half8;
typedef __attribute__((ext_vector_type(4))) float float4v;

#define S_DIM 2048
#define E_DIM 512
#define NROWS (8 * S_DIM)
#define SCALE 0.044194173824159216f

__device__ __forceinline__ float4v mfma16(short8 a, short8 b, float4v c) {
    return __builtin_amdgcn_mfma_f32_16x16x32_f16(
        __builtin_bit_cast(half8, a), __builtin_bit_cast(half8, b), c, 0, 0, 0);
}
__device__ __forceinline__ float bf2f(unsigned int u) {
    union { unsigned int i; float f; } v; v.i = u << 16; return v.f;
}
__device__ __forceinline__ u16 f2h_bits(float f) {
    union { _Float16 h; u16 u; } v; v.h = (_Float16)f; return v.u;
}
__device__ __forceinline__ float h2f(u16 u) {
    union { u16 u; _Float16 h; } v; v.u = u; return (float)v.h;
}
__device__ __forceinline__ int detect_bf16(const void* wp) {
    const u16* w = (const u16*)wp;
    int cnt = 0;
    for (int i = 0; i < 64; ++i) {
        int e = (w[2 * i] >> 7) & 0xff;
        cnt += (e >= 100 && e <= 131) ? 1 : 0;
    }
    return cnt >= 40;
}
__device__ __forceinline__ void load8(const void* base, size_t idx, int isbf, float* f) {
    if (isbf) {
        uint4 v = *(const uint4*)((const u16*)base + idx);
        f[0] = bf2f(v.x & 0xffffu); f[1] = bf2f(v.x >> 16);
        f[2] = bf2f(v.y & 0xffffu); f[3] = bf2f(v.y >> 16);
        f[4] = bf2f(v.z & 0xffffu); f[5] = bf2f(v.z >> 16);
        f[6] = bf2f(v.w & 0xffffu); f[7] = bf2f(v.w >> 16);
    } else {
        const float* p = (const float*)base + idx;
        float4 a = *(const float4*)p;
        float4 b = *(const float4*)(p + 4);
        f[0] = a.x; f[1] = a.y; f[2] = a.z; f[3] = a.w;
        f[4] = b.x; f[5] = b.y; f[6] = b.z; f[7] = b.w;
    }
}
__device__ __forceinline__ float load1(const void* base, size_t idx, int isbf) {
    return isbf ? bf2f(((const u16*)base)[idx]) : ((const float*)base)[idx];
}

// async 16B global -> LDS (per-lane src, wave-uniform LDS base + lane*16)
__device__ __forceinline__ void gld16(const u16* g, u16* l) {
    __builtin_amdgcn_global_load_lds(
        (const __attribute__((address_space(1))) void*)g,
        (__attribute__((address_space(3))) void*)l, 16, 0, 0);
}

// stage one 16B granule into LDS. C=0: f16 global, async gld16.
// C=1: fp32 global -> f16 (reg-staged). C=2: bf16 global -> f16 (reg-staged).
template<int C>
__device__ __forceinline__ void stage(const void* g, size_t off, u16* lds) {
    if constexpr (C == 0) {
        gld16((const u16*)g + off, lds);
    } else if constexpr (C == 1) {
        const float* p = (const float*)g + off;
        float4 a = *(const float4*)p;
        float4 b = *(const float4*)(p + 4);
        union { u16 h[8]; short8 v; } pk;
        pk.h[0] = f2h_bits(a.x); pk.h[1] = f2h_bits(a.y);
        pk.h[2] = f2h_bits(a.z); pk.h[3] = f2h_bits(a.w);
        pk.h[4] = f2h_bits(b.x); pk.h[5] = f2h_bits(b.y);
        pk.h[6] = f2h_bits(b.z); pk.h[7] = f2h_bits(b.w);
        *(short8*)lds = pk.v;
    } else {
        uint4 v = *(const uint4*)((const u16*)g + off);
        unsigned int uu[4] = {v.x, v.y, v.z, v.w};
        union { u16 h[8]; short8 v8; } pk;
#pragma unroll
        for (int j = 0; j < 4; ++j) {
            pk.h[2 * j]     = f2h_bits(bf2f(uu[j] & 0xffffu));
            pk.h[2 * j + 1] = f2h_bits(bf2f(uu[j] >> 16));
        }
        *(short8*)lds = pk.v8;
    }
}

// ---------------- conversion kernel (weights only; reads inputs, writes ws) ----
__global__ __launch_bounds__(256) void conv_w(
    const void* w0, const void* w1, const void* w2,
    const void* b0, const void* b1, const void* b2, u16* wb)
{
    const int z = blockIdx.y;
    const void* w = (z == 0) ? w0 : (z == 1) ? w1 : w2;
    const void* bb = (z == 0) ? b0 : (z == 1) ? b1 : b2;
    const int isbf = detect_bf16(w0);
    const size_t idx = ((size_t)blockIdx.x * 256 + threadIdx.x) * 8;
    float f[8];
    load8(w, idx, isbf, f);
    union { u16 h[8]; uint4 v; } pk;
#pragma unroll
    for (int j = 0; j < 8; ++j) pk.h[j] = f2h_bits(f[j]);
    *(uint4*)(wb + (size_t)z * 262144 + idx) = pk.v;
    if (blockIdx.x == 0) {
        u16* bbase = wb + 3 * 262144 + z * 512;
#pragma unroll
        for (int j = 0; j < 2; ++j) {
            int i = threadIdx.x * 2 + j;
            bbase[i] = f2h_bits(load1(bb, i, isbf));
        }
    }
}

// ---------------- shared GEMM core ----------------
// 128x128 tile, BK=32, 4 waves (2x2 of 64x64), m97 2-barrier K-loop.
// LDS layout: granule(16B) flat = 4*r + (kq ^ ((r>>1)&3))  -> 2-way max conflicts.
template<int ONES, int CA, int CB>
__device__ __forceinline__ void gemm_core(
    const void* __restrict__ A, int sA, const void* __restrict__ B, int sB, int K,
    u16* As, u16* Bs, float4v acc[4][4], float4v accS[4])
{
    const int t = threadIdx.x;
    const int w = t >> 6, l = t & 63;
    const int lane15 = l & 15, quad = l >> 4;
    const int wm = w & 1, wn = w >> 1;

    short8 ones;
#pragma unroll
    for (int j = 0; j < 8; ++j) ones[j] = (short)0x3C00;   // f16 1.0

    for (int kt = 0; kt < K; kt += 32) {
        __syncthreads();
#pragma unroll
        for (int i = 0; i < 2; ++i) {
            const int fg = w * 128 + i * 64 + l;
            const int r = fg >> 2;
            const int kq = (fg & 3) ^ ((r >> 1) & 3);
            stage<CA>(A, (size_t)r * sA + kt + kq * 8, As + fg * 8);
            stage<CB>(B, (size_t)r * sB + kt + kq * 8, Bs + fg * 8);
        }
        __syncthreads();

        short8 af[4], bf[4];
#pragma unroll
        for (int mi = 0; mi < 4; ++mi) {
            const int r = wm * 64 + mi * 16 + lane15;
            af[mi] = *(const short8*)&As[(4 * r + (quad ^ ((r >> 1) & 3))) * 8];
        }
#pragma unroll
        for (int ni = 0; ni < 4; ++ni) {
            const int r = wn * 64 + ni * 16 + lane15;
            bf[ni] = *(const short8*)&Bs[(4 * r + (quad ^ ((r >> 1) & 3))) * 8];
        }
#pragma unroll
        for (int mi = 0; mi < 4; ++mi) {
#pragma unroll
            for (int ni = 0; ni < 4; ++ni)
                acc[mi][ni] = mfma16(af[mi], bf[ni], acc[mi][ni]);
            if (ONES) accS[mi] = mfma16(af[mi], ones, accS[mi]);
        }
    }
}

#define GEMM_PRE()                                                     \
    __shared__ u16 As[4096] __attribute__((aligned(16)));              \
    __shared__ u16 Bs[4096] __attribute__((aligned(16)));              \
    const int t = threadIdx.x;                                         \
    const int w = t >> 6, l = t & 63;                                  \
    const int lane15 = l & 15, quad = l >> 4;                          \
    const int wm = w & 1, wn = w >> 1;                                 \
    (void)l; (void)w;                                                  \
    float4v acc[4][4];                                                 \
    float4v accS[4];                                                   \
    _Pragma("unroll") for (int mi = 0; mi < 4; ++mi) {                 \
        accS[mi] = (float4v){0.f, 0.f, 0.f, 0.f};                      \
        _Pragma("unroll") for (int ni = 0; ni < 4; ++ni)               \
            acc[mi][ni] = (float4v){0.f, 0.f, 0.f, 0.f};               \
    }

// ---------------- proj: Q, K, Vt ----------------
// z<2: A = x[m0..] (converted on the fly), B = wb[z][n0..]; C -> Q or K (f16, ws)
// z=2: A = wb[2][m0..], B = x[n0..] (converted on the fly); C -> Vt (f16, ws)
__global__ __launch_bounds__(256) void proj_gemm(
    const void* __restrict__ xorig, const void* __restrict__ wq_orig,
    const u16* __restrict__ wb,
    u16* __restrict__ qb, u16* __restrict__ kb, u16* __restrict__ vt)
{
    GEMM_PRE();
    const int z = blockIdx.z;
    const int isbf = detect_bf16(wq_orig);
    const u16* bias = wb + 3 * 262144 + z * 512;

    int m0, n0;
    if (z < 2) { m0 = blockIdx.y * 128; n0 = blockIdx.x * 128; }
    else       { m0 = blockIdx.x * 128; n0 = blockIdx.y * 128; }

    if (z < 2) {
        const void* A = isbf ? (const void*)((const u16*)xorig + (size_t)m0 * 512)
                             : (const void*)((const float*)xorig + (size_t)m0 * 512);
        const void* B = wb + (size_t)z * 262144 + (size_t)n0 * 512;
        if (isbf) gemm_core<0, 2, 0>(A, 512, B, 512, 512, As, Bs, acc, accS);
        else      gemm_core<0, 1, 0>(A, 512, B, 512, 512, As, Bs, acc, accS);
    } else {
        const void* A = wb + (size_t)2 * 262144 + (size_t)m0 * 512;
        const void* B = isbf ? (const void*)((const u16*)xorig + (size_t)n0 * 512)
                             : (const void*)((const float*)xorig + (size_t)n0 * 512);
        if (isbf) gemm_core<0, 0, 2>(A, 512, B, 512, 512, As, Bs, acc, accS);
        else      gemm_core<0, 0, 1>(A, 512, B, 512, 512, As, Bs, acc, accS);
    }

    if (z < 2) {
        u16* dst = z ? kb : qb;
        float bcol[4];
#pragma unroll
        for (int ni = 0; ni < 4; ++ni)
            bcol[ni] = h2f(bias[n0 + wn * 64 + ni * 16 + lane15]);
#pragma unroll
        for (int mi = 0; mi < 4; ++mi)
#pragma unroll
            for (int ni = 0; ni < 4; ++ni)
#pragma unroll
                for (int r = 0; r < 4; ++r) {
                    const int row = m0 + wm * 64 + mi * 16 + quad * 4 + r;
                    const int col = n0 + wn * 64 + ni * 16 + lane15;
                    dst[(size_t)row * 512 + col] = f2h_bits(acc[mi][ni][r] + bcol[ni]);
                }
    } else {
#pragma unroll
        for (int mi = 0; mi < 4; ++mi)
#pragma unroll
            for (int r = 0; r < 4; ++r) {
                const int e = m0 + wm * 64 + mi * 16 + quad * 4 + r;      // 0..511
                const float bias_e = h2f(bias[e]);
#pragma unroll
                for (int ni = 0; ni < 4; ++ni) {
                    const int tok = n0 + wn * 64 + ni * 16 + lane15;
                    vt[((size_t)(tok >> 11) * 512 + e) * 2048 + (tok & 2047)] =
                        f2h_bits(acc[mi][ni][r] + bias_e);
                }
            }
    }
}

// ---------------- gemmS: S = exp(masked(Q.K^T * scale)) f16, phased ----------
__global__ __launch_bounds__(256) void gemmS(
    const u16* __restrict__ qb, const u16* __restrict__ kb,
    const int* __restrict__ mask, u16* __restrict__ Sdst, int b0)
{
    GEMM_PRE();
    const int zb = blockIdx.z;
    const int b = b0 + zb;
    const int m0 = blockIdx.y * 128, n0 = blockIdx.x * 128;
    const u16* A = qb + (size_t)(b * S_DIM + m0) * 512;
    const u16* B = kb + (size_t)(b * S_DIM + n0) * 512;

    gemm_core<0, 0, 0>(A, 512, B, 512, 512, As, Bs, acc, accS);

    u16* Sb = Sdst + (size_t)zb * S_DIM * S_DIM;
#pragma unroll
    for (int mi = 0; mi < 4; ++mi)
#pragma unroll
        for (int r = 0; r < 4; ++r) {
            const int row = m0 + wm * 64 + mi * 16 + quad * 4 + r;
            const int col0 = n0 + wn * 64 + lane15;
            int mk[4];
#pragma unroll
            for (int ni = 0; ni < 4; ++ni)
                mk[ni] = mask[((size_t)b * S_DIM + row) * S_DIM + col0 + ni * 16];
#pragma unroll
            for (int ni = 0; ni < 4; ++ni) {
                const float p = (mk[ni] > 0) ? 0.f : __expf(acc[mi][ni][r] * SCALE);
                Sb[(size_t)row * S_DIM + col0 + ni * 16] = f2h_bits(p);
            }
        }
}

// ---------------- gemmO: out = (S @ Vt) / rowsum(S), phased ----------------
__global__ __launch_bounds__(256) void gemmO(
    const u16* __restrict__ Ssrc, const u16* __restrict__ vt,
    float* __restrict__ outp, int b0)
{
    GEMM_PRE();
    const int zb = blockIdx.z;
    const int b = b0 + zb;
    const int m0 = blockIdx.y * 128, n0 = blockIdx.x * 128;
    const u16* A = Ssrc + (size_t)zb * S_DIM * S_DIM + (size_t)m0 * S_DIM;
    const u16* B = vt + ((size_t)b * 512 + n0) * 2048;

    gemm_core<1, 0, 0>(A, S_DIM, B, S_DIM, S_DIM, As, Bs, acc, accS);

#pragma unroll
    for (int mi = 0; mi < 4; ++mi)
#pragma unroll
        for (int r = 0; r < 4; ++r) {
            const int row = m0 + wm * 64 + mi * 16 + quad * 4 + r;
            const float inv = 1.f / accS[mi][r];
#pragma unroll
            for (int ni = 0; ni < 4; ++ni) {
                const int col = n0 + wn * 64 + ni * 16 + lane15;
                outp[((size_t)b * S_DIM + row) * E_DIM + col] = acc[mi][ni][r] * inv;
            }
        }
}

extern "C" void kernel_launch(void* const* d_in, const int* in_sizes, int n_in,
                              void* d_out, int out_size, void* d_ws, size_t ws_size,
                              hipStream_t stream) {
    const void* x    = d_in[0];
    const int*  mask = (const int*)d_in[1];
    const void* wq   = d_in[2];
    const void* bq   = d_in[3];
    const void* wk   = d_in[4];
    const void* bk   = d_in[5];
    const void* wv   = d_in[6];
    const void* bv   = d_in[7];

    const size_t MB   = 1ull << 20;
    const size_t QSZ  = (size_t)NROWS * E_DIM;          // u16 elems per Q/K/Vt (16.8 MB)
    const size_t S_PB = (size_t)S_DIM * S_DIM;          // u16 elems per S batch (8.4 MB)

    u16* wb  = (u16*)d_ws;                              // 2 MB region (weights+bias f16)
    u16* qb  = (u16*)((char*)d_ws + 2 * MB);
    u16* kb  = qb + QSZ;
    u16* vtb = kb + QSZ;
    u16* sS  = vtb + QSZ;                               // S scratch, phased

    const size_t used = 2 * MB + 3 * QSZ * 2;           // 52.4 MB fixed
    const size_t availB = (ws_size > used) ? (ws_size - used) / (S_PB * 2) : 1;
    const int P = (availB >= 8) ? 8 : (availB >= 4) ? 4 : (availB >= 2) ? 2 : 1;

    conv_w<<<dim3(128, 3), 256, 0, stream>>>(wq, wk, wv, bq, bk, bv, wb);

    proj_gemm<<<dim3(4, 128, 3), 256, 0, stream>>>(x, wq, wb, qb, kb, vtb);

    for (int p = 0; p < 8; p += P) {
        gemmS<<<dim3(16, 16, P), 256, 0, stream>>>(qb, kb, mask, sS, p);
        gemmO<<<dim3(4, 16, P), 256, 0, stream>>>(sS, vtb, (float*)d_out, p);
    }
}